// Round 2
// baseline (509.873 us; speedup 1.0000x reference)
//
#include <hip/hip_runtime.h>
#include <math.h>

#define HH 512
#define WW 512
#define NPIX (HH*WW)
#define NB 32
#define NS 21           // 2*MS+1 shifts per axis
#define KWIN 492        // window size (H - 2*10)

// ---------------- Kernel R: per-image sums (32 frames + template as #32) ----
__global__ __launch_bounds__(256) void sum_kernel(
    const float* __restrict__ fr, const float* __restrict__ tpl,
    double* __restrict__ sum1, double* __restrict__ sum2)
{
    int n = blockIdx.x;          // 0..527  (33 images * 16 chunks)
    int im = n >> 4;
    int chunk = n & 15;
    const float* src = (im < NB) ? (fr + (size_t)im * NPIX) : tpl;
    const float4* p = (const float4*)(src + chunk * 16384);
    double s1 = 0.0, s2 = 0.0;
    for (int i = threadIdx.x; i < 4096; i += 256) {
        float4 q = p[i];
        s1 += (double)q.x + (double)q.y + (double)q.z + (double)q.w;
        s2 += (double)q.x*q.x + (double)q.y*q.y + (double)q.z*q.z + (double)q.w*q.w;
    }
    for (int off = 32; off; off >>= 1) {
        s1 += __shfl_down(s1, off);
        s2 += __shfl_down(s2, off);
    }
    __shared__ double ls1[4], ls2[4];
    int lane = threadIdx.x & 63, wv = threadIdx.x >> 6;
    if (lane == 0) { ls1[wv] = s1; ls2[wv] = s2; }
    __syncthreads();
    if (threadIdx.x == 0) {
        atomicAdd(&sum1[im], ls1[0]+ls1[1]+ls1[2]+ls1[3]);
        atomicAdd(&sum2[im], ls2[0]+ls2[1]+ls2[2]+ls2[3]);
    }
}

// ---------------- Kernel W1: sliding column sums over y-windows -------------
// For each (b,x): colsum[u] = sum_{y=u}^{u+491} img[y,x], u in [0,21), plus squares.
__global__ __launch_bounds__(256) void colsum_kernel(
    const float* __restrict__ fr, float* __restrict__ cs1, float* __restrict__ cs2)
{
    int tid = blockIdx.x * 256 + threadIdx.x;   // 0..16383
    int b = tid >> 9;
    int x = tid & 511;
    const float* img = fr + (size_t)b * NPIX + x;
    float lo[20], hi[20];
    double s1 = 0.0, s2 = 0.0;
#pragma unroll
    for (int y = 0; y < 20; ++y) {
        float v = img[(size_t)y * WW];
        lo[y] = v; s1 += (double)v; s2 += (double)v * v;
    }
    for (int y = 20; y < 492; ++y) {
        float v = img[(size_t)y * WW];
        s1 += (double)v; s2 += (double)v * v;
    }
#pragma unroll
    for (int y = 0; y < 20; ++y) hi[y] = img[(size_t)(492 + y) * WW];

    size_t base = (size_t)b * NS * WW + x;
    cs1[base] = (float)s1; cs2[base] = (float)s2;
#pragma unroll
    for (int u = 1; u < NS; ++u) {
        float a = lo[u-1], c = hi[u-1];
        s1 += (double)c - (double)a;
        s2 += (double)c * c - (double)a * a;
        cs1[base + (size_t)u * WW] = (float)s1;
        cs2[base + (size_t)u * WW] = (float)s2;
    }
}

// ---------------- Kernel W2: window sums -> denominator ---------------------
__global__ __launch_bounds__(256) void denom_kernel(
    const float* __restrict__ cs1, const float* __restrict__ cs2,
    const double* __restrict__ sum1, const double* __restrict__ sum2,
    float* __restrict__ denom)
{
    int tid = blockIdx.x * 256 + threadIdx.x;   // (b*21+u)*21+v, < 14112
    if (tid >= NB * NS * NS) return;
    int v  = tid % NS;
    int bu = tid / NS;
    const float* r1 = cs1 + (size_t)bu * WW + v;
    const float* r2 = cs2 + (size_t)bu * WW + v;
    double s1 = 0.0, s2 = 0.0;
    for (int x = 0; x < KWIN; ++x) { s1 += (double)r1[x]; s2 += (double)r2[x]; }
    const double inv = 1.0 / ((double)KWIN * (double)KWIN);
    double m1 = s1 * inv, m2 = s2 * inv;
    double var = m2 - (m1 * m1) * inv + 1e-8;   // reference's (odd) formula
    if (var < 0.0) var = 0.0;
    double tv = sum2[32] - sum1[32] * sum1[32] * (1.0 / (double)NPIX) + 1e-8;
    denom[tid] = (float)sqrt(tv * var);
}

// ---------------- Kernel C: direct circular cross-correlation ---------------
// cc[b][u][v] = sum_{y,x} (img[y,x]-mb) * (tpl[(y-(u-10))&511, (x-(v-10))&511]-mt)
// Block: (b, u, row-quarter). Each wave stages its own template row in LDS;
// cross-lane reads REQUIRE a barrier (compiler may reorder otherwise).
__global__ __launch_bounds__(256) void corr_kernel(
    const float* __restrict__ fr, const float* __restrict__ tpl,
    const double* __restrict__ sums, float* __restrict__ cc)
{
    int n = blockIdx.x;            // 0..2687
    int b   = n / 84;
    int rem = n % 84;
    int u  = rem >> 2;
    int rq = rem & 3;
    int ybase = rq * 128;

    const int t = threadIdx.x;
    const int g = t & 63;          // x-group within wave
    const int r = t >> 6;          // wave id = row subgroup
    const int x0 = g * 8;

    const float mb = (float)(sums[b]  * (1.0 / (double)NPIX));
    const float mt = (float)(sums[32] * (1.0 / (double)NPIX));

    __shared__ __align__(16) float tl[4][544];   // template row, zero-mean, +/-16 wrap margin
    __shared__ float red[4][NS];

    const float* img = fr + (size_t)b * NPIX;

    float acc[NS];
#pragma unroll
    for (int v = 0; v < NS; ++v) acc[v] = 0.f;

    for (int k = 0; k < 32; ++k) {
        int y  = ybase + k * 4 + r;
        int ty = (y - u + 10 + 512) & 511;       // (y - dy) mod 512, dy = u-10
        const float* trow = tpl + (size_t)ty * WW;

        // stage: wave r fills tl[r] (each lane 2 float4s + margins)
        {
            float4 a0 = *(const float4*)(trow + x0);
            float4 a1 = *(const float4*)(trow + x0 + 4);
            a0.x -= mt; a0.y -= mt; a0.z -= mt; a0.w -= mt;
            a1.x -= mt; a1.y -= mt; a1.z -= mt; a1.w -= mt;
            *(float4*)&tl[r][16 + x0]     = a0;
            *(float4*)&tl[r][16 + x0 + 4] = a1;
            if (g < 4) {        // left margin: trow[496..512)
                float4 m = *(const float4*)(trow + 496 + 4 * g);
                m.x -= mt; m.y -= mt; m.z -= mt; m.w -= mt;
                *(float4*)&tl[r][4 * g] = m;
            }
            if (g >= 60) {      // right margin: trow[0..16)
                float4 m = *(const float4*)(trow + 4 * (g - 60));
                m.x -= mt; m.y -= mt; m.z -= mt; m.w -= mt;
                *(float4*)&tl[r][528 + 4 * (g - 60)] = m;
            }
        }
        __syncthreads();   // cross-lane LDS visibility (compiler + HW ordering)

        float4 i0 = *(const float4*)(img + (size_t)y * WW + x0);
        float4 i1 = *(const float4*)(img + (size_t)y * WW + x0 + 4);
        float im8[8] = { i0.x - mb, i0.y - mb, i0.z - mb, i0.w - mb,
                         i1.x - mb, i1.y - mb, i1.z - mb, i1.w - mb };
        float w[32];           // w[m] = tzm[x0 - 12 + m]
#pragma unroll
        for (int j = 0; j < 8; ++j) {
            float4 q = *(const float4*)&tl[r][x0 + 4 + j * 4];
            w[4*j] = q.x; w[4*j+1] = q.y; w[4*j+2] = q.z; w[4*j+3] = q.w;
        }
#pragma unroll
        for (int v = 0; v < NS; ++v) {
            float s = acc[v];
#pragma unroll
            for (int j = 0; j < 8; ++j)
                s += im8[j] * w[j + 22 - v];     // tzm index x0+j-(v-10)
            acc[v] = s;
        }
        __syncthreads();   // WAR: next iteration re-writes tl
    }

    // reduce 64 lanes -> 4 waves -> atomic
#pragma unroll
    for (int v = 0; v < NS; ++v) {
        float s = acc[v];
        for (int off = 32; off; off >>= 1) s += __shfl_down(s, off);
        if (g == 0) red[r][v] = s;
    }
    __syncthreads();
    if (t < NS) {
        float s = red[0][t] + red[1][t] + red[2][t] + red[3][t];
        atomicAdd(&cc[((size_t)b * NS + u) * NS + t], s);
    }
}

// ---------------- Kernel S: argmax + log-parabola subpixel ------------------
__global__ __launch_bounds__(64) void argmax_kernel(
    const float* __restrict__ cc, const float* __restrict__ denom,
    float* __restrict__ shifts)
{
    int b = blockIdx.x;
    const float* C = cc    + (size_t)b * NS * NS;
    const float* D = denom + (size_t)b * NS * NS;
    int l = threadIdx.x;
    float best = -1e30f; int bidx = NS * NS;
    for (int i = l; i < NS * NS; i += 64) {
        float v = fabsf(C[i]) / D[i];
        if (v != v) v = 0.f;               // NaN -> 0 (matches reference)
        if (v > best) { best = v; bidx = i; }
    }
    for (int off = 32; off; off >>= 1) {
        float ov = __shfl_down(best, off);
        int   oi = __shfl_down(bidx, off);
        if (ov > best || (ov == best && oi < bidx)) { best = ov; bidx = oi; }
    }
    if (l == 0) {
        int shx = bidx / NS, shy = bidx % NS;
        auto nccAt = [&](int i, int j) -> float {
            i = (i < 0) ? i + NS : i; i = (i > NS - 1) ? NS - 1 : i;  // jnp wrap-then-clamp
            j = (j < 0) ? j + NS : j; j = (j > NS - 1) ? NS - 1 : j;
            float v = fabsf(C[i * NS + j]) / D[i * NS + j];
            if (v != v) v = 0.f;
            return v;
        };
        float lc  = logf(nccAt(shx, shy));
        float lxm = logf(nccAt(shx - 1, shy));
        float lxp = logf(nccAt(shx + 1, shy));
        float lym = logf(nccAt(shx, shy - 1));
        float lyp = logf(nccAt(shx, shy + 1));
        float shxn = -(float)(shx - 10) - (lxm - lxp) / (2.f * lxm - 4.f * lc + 2.f * lxp);
        float shyn = -(float)(shy - 10) - (lym - lyp) / (2.f * lym - 4.f * lc + 2.f * lyp);
        shifts[b]      = shxn;   // dy
        shifts[32 + b] = shyn;   // dx
    }
}

// ---------------- Kernel B: bilinear warp + transposed write ----------------
__device__ __forceinline__ float samp(const float* __restrict__ img, int y, int x) {
    bool valid = (y >= 0) & (y < HH) & (x >= 0) & (x < WW);
    int yc = min(max(y, 0), HH - 1), xc = min(max(x, 0), WW - 1);
    float v = img[(size_t)yc * WW + xc];
    return valid ? v : 0.f;
}

__global__ __launch_bounds__(256) void warp_kernel(
    const float* __restrict__ fr, const float* __restrict__ shifts,
    float* __restrict__ out)
{
    int b  = blockIdx.z;
    int h0 = blockIdx.y * 32;
    int w0 = blockIdx.x * 32;
    float dy = shifts[b], dx = shifts[32 + b];
    const float* img = fr + (size_t)b * NPIX;
    __shared__ float tile[32][33];
    int tx = threadIdx.x & 31;
    int tz = threadIdx.x >> 5;
#pragma unroll
    for (int s = 0; s < 4; ++s) {
        int h = h0 + tz + 8 * s;
        int w = w0 + tx;
        float yq = (float)h - dy;
        float xq = (float)w - dx;
        float y0f = floorf(yq), x0f = floorf(xq);
        float wy = yq - y0f, wx = xq - x0f;
        int y0 = (int)y0f, x0 = (int)x0f;
        float v00 = samp(img, y0,     x0);
        float v01 = samp(img, y0,     x0 + 1);
        float v10 = samp(img, y0 + 1, x0);
        float v11 = samp(img, y0 + 1, x0 + 1);
        float val = v00 * (1.f - wy) * (1.f - wx) + v01 * (1.f - wy) * wx
                  + v10 * wy * (1.f - wx)         + v11 * wy * wx;
        tile[tz + 8 * s][tx] = val;
    }
    __syncthreads();
#pragma unroll
    for (int s = 0; s < 4; ++s) {
        int hh = tx;
        int ww = tz + 8 * s;
        out[(size_t)b * NPIX + (size_t)(w0 + ww) * HH + (h0 + hh)] = tile[hh][ww];
    }
}

// ---------------- launch ----------------------------------------------------
extern "C" void kernel_launch(void* const* d_in, const int* in_sizes, int n_in,
                              void* d_out, int out_size, void* d_ws, size_t ws_size,
                              hipStream_t stream) {
    const float* fr  = (const float*)d_in[0];   // (1,32,512,512,1) flat
    const float* tpl = (const float*)d_in[1];   // (512,512)
    float* out = (float*)d_out;
    char* ws = (char*)d_ws;

    // ws layout (total ~2.9 MB)
    double* sum1   = (double*)(ws + 0);          // 33 doubles
    double* sum2   = (double*)(ws + 512);        // 33 doubles
    float*  cc     = (float*) (ws + 4096);       // 32*441 floats (zeroed)
    float*  shifts = (float*) (ws + 61440);      // 64 floats
    float*  denom  = (float*) (ws + 65536);      // 32*441 floats
    float*  cs1    = (float*) (ws + 131072);     // 32*21*512 floats
    float*  cs2    = (float*) (ws + 1507328);    // 32*21*512 floats

    hipMemsetAsync(ws, 0, 61440, stream);        // zero sums + cc

    sum_kernel   <<<528, 256, 0, stream>>>(fr, tpl, sum1, sum2);
    colsum_kernel<<<64, 256, 0, stream>>>(fr, cs1, cs2);
    denom_kernel <<<(NB * NS * NS + 255) / 256, 256, 0, stream>>>(cs1, cs2, sum1, sum2, denom);
    corr_kernel  <<<2688, 256, 0, stream>>>(fr, tpl, sum1, cc);
    argmax_kernel<<<32, 64, 0, stream>>>(cc, denom, shifts);
    warp_kernel  <<<dim3(16, 16, 32), 256, 0, stream>>>(fr, shifts, out);
}

// Round 3
// 405.999 us; speedup vs baseline: 1.2558x; 1.2558x over previous
//
#include <hip/hip_runtime.h>
#include <math.h>

#define HH 512
#define WW 512
#define NPIX (HH*WW)
#define NB 32
#define NS 21           // 2*MS+1 shifts per axis
#define KWIN 492        // window size (H - 2*10)

// ---------------- Kernel R: per-image sums (32 frames + template as #32) ----
__global__ __launch_bounds__(256) void sum_kernel(
    const float* __restrict__ fr, const float* __restrict__ tpl,
    double* __restrict__ sum1, double* __restrict__ sum2)
{
    int n = blockIdx.x;          // 0..527  (33 images * 16 chunks)
    int im = n >> 4;
    int chunk = n & 15;
    const float* src = (im < NB) ? (fr + (size_t)im * NPIX) : tpl;
    const float4* p = (const float4*)(src + chunk * 16384);
    double s1 = 0.0, s2 = 0.0;
    for (int i = threadIdx.x; i < 4096; i += 256) {
        float4 q = p[i];
        s1 += (double)q.x + (double)q.y + (double)q.z + (double)q.w;
        s2 += (double)q.x*q.x + (double)q.y*q.y + (double)q.z*q.z + (double)q.w*q.w;
    }
    for (int off = 32; off; off >>= 1) {
        s1 += __shfl_down(s1, off);
        s2 += __shfl_down(s2, off);
    }
    __shared__ double ls1[4], ls2[4];
    int lane = threadIdx.x & 63, wv = threadIdx.x >> 6;
    if (lane == 0) { ls1[wv] = s1; ls2[wv] = s2; }
    __syncthreads();
    if (threadIdx.x == 0) {
        atomicAdd(&sum1[im], ls1[0]+ls1[1]+ls1[2]+ls1[3]);
        atomicAdd(&sum2[im], ls2[0]+ls2[1]+ls2[2]+ls2[3]);
    }
}

// ---------------- Kernel W1: sliding column sums over y-windows -------------
__global__ __launch_bounds__(256) void colsum_kernel(
    const float* __restrict__ fr, float* __restrict__ cs1, float* __restrict__ cs2)
{
    int tid = blockIdx.x * 256 + threadIdx.x;   // 0..16383
    int b = tid >> 9;
    int x = tid & 511;
    const float* img = fr + (size_t)b * NPIX + x;
    float lo[20], hi[20];
    double s1 = 0.0, s2 = 0.0;
#pragma unroll
    for (int y = 0; y < 20; ++y) {
        float v = img[(size_t)y * WW];
        lo[y] = v; s1 += (double)v; s2 += (double)v * v;
    }
    for (int y = 20; y < 492; ++y) {
        float v = img[(size_t)y * WW];
        s1 += (double)v; s2 += (double)v * v;
    }
#pragma unroll
    for (int y = 0; y < 20; ++y) hi[y] = img[(size_t)(492 + y) * WW];

    size_t base = (size_t)b * NS * WW + x;
    cs1[base] = (float)s1; cs2[base] = (float)s2;
#pragma unroll
    for (int u = 1; u < NS; ++u) {
        float a = lo[u-1], c = hi[u-1];
        s1 += (double)c - (double)a;
        s2 += (double)c * c - (double)a * a;
        cs1[base + (size_t)u * WW] = (float)s1;
        cs2[base + (size_t)u * WW] = (float)s2;
    }
}

// ---------------- Kernel W2: window sums -> denominator (wave per triple) ---
__global__ __launch_bounds__(256) void denom_kernel(
    const float* __restrict__ cs1, const float* __restrict__ cs2,
    const double* __restrict__ sum1, const double* __restrict__ sum2,
    float* __restrict__ denom)
{
    int wid  = blockIdx.x * 4 + (threadIdx.x >> 6);   // one wave per (b,u,v)
    int lane = threadIdx.x & 63;
    if (wid >= NB * NS * NS) return;
    int v  = wid % NS;
    int bu = wid / NS;
    const float* r1 = cs1 + (size_t)bu * WW + v;
    const float* r2 = cs2 + (size_t)bu * WW + v;
    double s1 = 0.0, s2 = 0.0;
    for (int x = lane; x < KWIN; x += 64) { s1 += (double)r1[x]; s2 += (double)r2[x]; }
    for (int off = 32; off; off >>= 1) {
        s1 += __shfl_down(s1, off);
        s2 += __shfl_down(s2, off);
    }
    if (lane == 0) {
        const double inv = 1.0 / ((double)KWIN * (double)KWIN);
        double m1 = s1 * inv, m2 = s2 * inv;
        double var = m2 - (m1 * m1) * inv + 1e-8;   // reference's formula
        if (var < 0.0) var = 0.0;
        double tv = sum2[32] - sum1[32] * sum1[32] * (1.0 / (double)NPIX) + 1e-8;
        denom[wid] = (float)sqrt(tv * var);
    }
}

// ---------------- Kernel C: direct circular cross-correlation ---------------
// cc[b][u][v] = sum_{y,x} (img[y,x]-mb) * (tpl[(y-(u-10))&511, (x-(v-10))&511]-mt)
// Block = (b, u, 128-row quarter). 8 template rows staged per phase as
// [16 wrap | 512 | 16 wrap], all LDS traffic at 16B lane stride (conflict-free).
// Each lane owns 4 pixels; 2 waves per image row.
__global__ __launch_bounds__(256) void corr_kernel(
    const float* __restrict__ fr, const float* __restrict__ tpl,
    const double* __restrict__ sums, float* __restrict__ cc)
{
    int n = blockIdx.x;            // 0..2687
    int b   = n / 84;
    int rem = n % 84;
    int u  = rem >> 2;
    int rq = rem & 3;
    int ybase = rq * 128;

    const int t  = threadIdx.x;
    const int g  = t & 63;         // lane
    const int wv = t >> 6;         // wave 0..3
    const int xh = wv & 1;         // x half
    const int rh = wv >> 1;        // row parity
    const int x0 = 4 * g + 256 * xh;

    const float mb = (float)(sums[b]  * (1.0 / (double)NPIX));
    const float mt = (float)(sums[32] * (1.0 / (double)NPIX));

    __shared__ __align__(16) float tl[8][544];   // 8 zero-mean template rows w/ wrap margins
    __shared__ float red[4][NS];

    const float* img = fr + (size_t)b * NPIX;

    float acc[NS];
#pragma unroll
    for (int v = 0; v < NS; ++v) acc[v] = 0.f;

    for (int ph = 0; ph < 16; ++ph) {
        int y0 = ybase + 8 * ph;

        // ---- stage 8 rows: wave wv fills slots 2*wv, 2*wv+1 ----
#pragma unroll
        for (int s = 0; s < 2; ++s) {
            int slot = 2 * wv + s;
            int ty = (y0 + slot - u + 10 + 512) & 511;
            const float* trow = tpl + (size_t)ty * WW;
            // chunk c -> LDS floats [4c,4c+4) <- template floats ((4c-16)&511 ..)
            {
                int c = g;
                float4 q = *(const float4*)(trow + ((4 * c - 16) & 511));
                q.x -= mt; q.y -= mt; q.z -= mt; q.w -= mt;
                *(float4*)&tl[slot][4 * c] = q;
            }
            {
                int c = 64 + g;
                float4 q = *(const float4*)(trow + ((4 * c - 16) & 511));
                q.x -= mt; q.y -= mt; q.z -= mt; q.w -= mt;
                *(float4*)&tl[slot][4 * c] = q;
            }
            if (g < 8) {
                int c = 128 + g;
                float4 q = *(const float4*)(trow + ((4 * c - 16) & 511));
                q.x -= mt; q.y -= mt; q.z -= mt; q.w -= mt;
                *(float4*)&tl[slot][4 * c] = q;
            }
        }
        __syncthreads();

        // ---- compute 8 rows: each step, waves {0,1} do row 2s, {2,3} row 2s+1
#pragma unroll
        for (int s = 0; s < 4; ++s) {
            int rp = 2 * s + rh;
            int y  = y0 + rp;
            float4 iv = *(const float4*)(img + (size_t)y * WW + x0);
            float im4[4] = { iv.x - mb, iv.y - mb, iv.z - mb, iv.w - mb };
            float wbuf[28];          // wbuf[m] = tzm[(x0 - 12 + m) & 511]
            const float* row = &tl[rp][0];
#pragma unroll
            for (int j = 0; j < 7; ++j) {
                float4 q = *(const float4*)(row + x0 + 4 + 4 * j);  // 16B lane stride
                wbuf[4*j] = q.x; wbuf[4*j+1] = q.y; wbuf[4*j+2] = q.z; wbuf[4*j+3] = q.w;
            }
#pragma unroll
            for (int v = 0; v < NS; ++v) {
                float sv = acc[v];
#pragma unroll
                for (int p = 0; p < 4; ++p)
                    sv += im4[p] * wbuf[p + 22 - v];   // tzm index x0+p-(v-10)
                acc[v] = sv;
            }
        }
        __syncthreads();   // WAR before next staging
    }

    // reduce 64 lanes -> 4 waves -> atomic
#pragma unroll
    for (int v = 0; v < NS; ++v) {
        float sv = acc[v];
        for (int off = 32; off; off >>= 1) sv += __shfl_down(sv, off);
        if (g == 0) red[wv][v] = sv;
    }
    __syncthreads();
    if (t < NS) {
        float sv = red[0][t] + red[1][t] + red[2][t] + red[3][t];
        atomicAdd(&cc[((size_t)b * NS + u) * NS + t], sv);
    }
}

// ---------------- Kernel S: argmax + log-parabola subpixel ------------------
__global__ __launch_bounds__(64) void argmax_kernel(
    const float* __restrict__ cc, const float* __restrict__ denom,
    float* __restrict__ shifts)
{
    int b = blockIdx.x;
    const float* C = cc    + (size_t)b * NS * NS;
    const float* D = denom + (size_t)b * NS * NS;
    int l = threadIdx.x;
    float best = -1e30f; int bidx = NS * NS;
    for (int i = l; i < NS * NS; i += 64) {
        float v = fabsf(C[i]) / D[i];
        if (v != v) v = 0.f;               // NaN -> 0 (matches reference)
        if (v > best) { best = v; bidx = i; }
    }
    for (int off = 32; off; off >>= 1) {
        float ov = __shfl_down(best, off);
        int   oi = __shfl_down(bidx, off);
        if (ov > best || (ov == best && oi < bidx)) { best = ov; bidx = oi; }
    }
    if (l == 0) {
        int shx = bidx / NS, shy = bidx % NS;
        auto nccAt = [&](int i, int j) -> float {
            i = (i < 0) ? i + NS : i; i = (i > NS - 1) ? NS - 1 : i;  // jnp wrap-then-clamp
            j = (j < 0) ? j + NS : j; j = (j > NS - 1) ? NS - 1 : j;
            float v = fabsf(C[i * NS + j]) / D[i * NS + j];
            if (v != v) v = 0.f;
            return v;
        };
        float lc  = logf(nccAt(shx, shy));
        float lxm = logf(nccAt(shx - 1, shy));
        float lxp = logf(nccAt(shx + 1, shy));
        float lym = logf(nccAt(shx, shy - 1));
        float lyp = logf(nccAt(shx, shy + 1));
        float shxn = -(float)(shx - 10) - (lxm - lxp) / (2.f * lxm - 4.f * lc + 2.f * lxp);
        float shyn = -(float)(shy - 10) - (lym - lyp) / (2.f * lym - 4.f * lc + 2.f * lyp);
        shifts[b]      = shxn;   // dy
        shifts[32 + b] = shyn;   // dx
    }
}

// ---------------- Kernel B: bilinear warp + transposed write ----------------
__device__ __forceinline__ float samp(const float* __restrict__ img, int y, int x) {
    bool valid = (y >= 0) & (y < HH) & (x >= 0) & (x < WW);
    int yc = min(max(y, 0), HH - 1), xc = min(max(x, 0), WW - 1);
    float v = img[(size_t)yc * WW + xc];
    return valid ? v : 0.f;
}

__global__ __launch_bounds__(256) void warp_kernel(
    const float* __restrict__ fr, const float* __restrict__ shifts,
    float* __restrict__ out)
{
    int b  = blockIdx.z;
    int h0 = blockIdx.y * 32;
    int w0 = blockIdx.x * 32;
    float dy = shifts[b], dx = shifts[32 + b];
    const float* img = fr + (size_t)b * NPIX;
    __shared__ float tile[32][33];
    int tx = threadIdx.x & 31;
    int tz = threadIdx.x >> 5;
#pragma unroll
    for (int s = 0; s < 4; ++s) {
        int h = h0 + tz + 8 * s;
        int w = w0 + tx;
        float yq = (float)h - dy;
        float xq = (float)w - dx;
        float y0f = floorf(yq), x0f = floorf(xq);
        float wy = yq - y0f, wx = xq - x0f;
        int y0 = (int)y0f, x0 = (int)x0f;
        float v00 = samp(img, y0,     x0);
        float v01 = samp(img, y0,     x0 + 1);
        float v10 = samp(img, y0 + 1, x0);
        float v11 = samp(img, y0 + 1, x0 + 1);
        float val = v00 * (1.f - wy) * (1.f - wx) + v01 * (1.f - wy) * wx
                  + v10 * wy * (1.f - wx)         + v11 * wy * wx;
        tile[tz + 8 * s][tx] = val;
    }
    __syncthreads();
#pragma unroll
    for (int s = 0; s < 4; ++s) {
        int hh = tx;
        int ww = tz + 8 * s;
        out[(size_t)b * NPIX + (size_t)(w0 + ww) * HH + (h0 + hh)] = tile[hh][ww];
    }
}

// ---------------- launch ----------------------------------------------------
extern "C" void kernel_launch(void* const* d_in, const int* in_sizes, int n_in,
                              void* d_out, int out_size, void* d_ws, size_t ws_size,
                              hipStream_t stream) {
    const float* fr  = (const float*)d_in[0];   // (1,32,512,512,1) flat
    const float* tpl = (const float*)d_in[1];   // (512,512)
    float* out = (float*)d_out;
    char* ws = (char*)d_ws;

    // ws layout (total ~2.9 MB)
    double* sum1   = (double*)(ws + 0);          // 33 doubles
    double* sum2   = (double*)(ws + 512);        // 33 doubles
    float*  cc     = (float*) (ws + 4096);       // 32*441 floats (zeroed)
    float*  shifts = (float*) (ws + 61440);      // 64 floats
    float*  denom  = (float*) (ws + 65536);      // 32*441 floats
    float*  cs1    = (float*) (ws + 131072);     // 32*21*512 floats
    float*  cs2    = (float*) (ws + 1507328);    // 32*21*512 floats

    hipMemsetAsync(ws, 0, 61440, stream);        // zero sums + cc

    sum_kernel   <<<528, 256, 0, stream>>>(fr, tpl, sum1, sum2);
    colsum_kernel<<<64, 256, 0, stream>>>(fr, cs1, cs2);
    denom_kernel <<<(NB * NS * NS + 3) / 4, 256, 0, stream>>>(cs1, cs2, sum1, sum2, denom);
    corr_kernel  <<<2688, 256, 0, stream>>>(fr, tpl, sum1, cc);
    argmax_kernel<<<32, 64, 0, stream>>>(cc, denom, shifts);
    warp_kernel  <<<dim3(16, 16, 32), 256, 0, stream>>>(fr, shifts, out);
}

// Round 4
// 280.127 us; speedup vs baseline: 1.8202x; 1.4493x over previous
//
#include <hip/hip_runtime.h>
#include <math.h>

#define HH 512
#define WW 512
#define NPIX (HH*WW)
#define NB 32
#define NS 21           // 2*MS+1 shifts per axis
#define KWIN 492        // window size (H - 2*10)

// ---------------- Kernel W1: column window sums + global sums ---------------
// blocks 0..255: (b, x-octant) -> cs1/cs2 windows + frame total S_b
// blocks 256..263: template column sums -> S_t, St2
__global__ __launch_bounds__(64) void colsum_kernel(
    const float* __restrict__ fr, const float* __restrict__ tpl,
    float* __restrict__ cs1, float* __restrict__ cs2,
    double* __restrict__ sum1, double* __restrict__ sum2)
{
    int blk  = blockIdx.x;
    int lane = threadIdx.x;
    if (blk < 256) {
        int b = blk >> 3;
        int x = (blk & 7) * 64 + lane;
        const float* img = fr + (size_t)b * NPIX + x;
        float lo[20], hi[20];
        float s1 = 0.f, s2 = 0.f;
#pragma unroll
        for (int y = 0; y < 20; ++y) {
            float v = img[(size_t)y * WW];
            lo[y] = v; s1 += v; s2 += v * v;
        }
        for (int y = 20; y < 492; ++y) {
            float v = img[(size_t)y * WW];
            s1 += v; s2 += v * v;
        }
#pragma unroll
        for (int y = 0; y < 20; ++y) hi[y] = img[(size_t)(492 + y) * WW];

        // frame total (for the mean-correction in argmax)
        float tot = s1;
#pragma unroll
        for (int y = 0; y < 20; ++y) tot += hi[y];
        double d = (double)tot;
        for (int off = 32; off; off >>= 1) d += __shfl_down(d, off);
        if (lane == 0) atomicAdd(&sum1[b], d);

        size_t base = (size_t)b * NS * WW + x;
        cs1[base] = s1; cs2[base] = s2;
#pragma unroll
        for (int u = 1; u < NS; ++u) {
            float a = lo[u-1], c = hi[u-1];
            s1 += c - a;
            s2 += c * c - a * a;
            cs1[base + (size_t)u * WW] = s1;
            cs2[base + (size_t)u * WW] = s2;
        }
    } else {
        int x = (blk - 256) * 64 + lane;
        const float* t = tpl + x;
        float s1 = 0.f, s2 = 0.f;
        for (int y = 0; y < 512; ++y) {
            float v = t[(size_t)y * WW];
            s1 += v; s2 += v * v;
        }
        double d1 = (double)s1, d2 = (double)s2;
        for (int off = 32; off; off >>= 1) {
            d1 += __shfl_down(d1, off);
            d2 += __shfl_down(d2, off);
        }
        if (lane == 0) {
            atomicAdd(&sum1[32], d1);
            atomicAdd(&sum2[32], d2);
        }
    }
}

// ---------------- Kernel W2: window sums -> denominator (wave per triple) ---
__global__ __launch_bounds__(256) void denom_kernel(
    const float* __restrict__ cs1, const float* __restrict__ cs2,
    const double* __restrict__ sum1, const double* __restrict__ sum2,
    float* __restrict__ denom)
{
    int wid  = blockIdx.x * 4 + (threadIdx.x >> 6);   // one wave per (b,u,v)
    int lane = threadIdx.x & 63;
    if (wid >= NB * NS * NS) return;
    int v  = wid % NS;
    int bu = wid / NS;
    const float* r1 = cs1 + (size_t)bu * WW + v;
    const float* r2 = cs2 + (size_t)bu * WW + v;
    double s1 = 0.0, s2 = 0.0;
    for (int x = lane; x < KWIN; x += 64) { s1 += (double)r1[x]; s2 += (double)r2[x]; }
    for (int off = 32; off; off >>= 1) {
        s1 += __shfl_down(s1, off);
        s2 += __shfl_down(s2, off);
    }
    if (lane == 0) {
        const double inv = 1.0 / ((double)KWIN * (double)KWIN);
        double m1 = s1 * inv, m2 = s2 * inv;
        double var = m2 - (m1 * m1) * inv + 1e-8;   // reference's formula
        if (var < 0.0) var = 0.0;
        double tv = sum2[32] - sum1[32] * sum1[32] * (1.0 / (double)NPIX) + 1e-8;
        denom[wid] = (float)sqrt(tv * var);
    }
}

// ---------------- Kernel C: raw circular cross-correlation, LDS-free --------
// rawcc[b][u][v] = sum_{y,x} img[y,x] * tpl[(y-u+10)&511, (x-v+10)&511]
// (mean correction  - S_b*S_t/N  applied in argmax; exact identity.)
// Block = (b, u-triple, y-half). Wave streams 64 rows; template row read once
// per row (2 coalesced float4 + 20 __shfl halo) and reused for 3 u via a
// 3-buffer register ring. 504 FMA per row per lane. No LDS, no barriers.
__device__ __forceinline__ void load_wbuf(float (&w)[28], const float* __restrict__ tpl,
                                          int ty, int g)
{
    const float* trow = tpl + (size_t)ty * WW;
    float4 t0 = *(const float4*)(trow + 8 * g);
    float4 t1 = *(const float4*)(trow + 8 * g + 4);
    float a0 = t0.x, a1 = t0.y, a2 = t0.z, a3 = t0.w;
    float a4 = t1.x, a5 = t1.y, a6 = t1.z, a7 = t1.w;
    int gm1 = (g + 63) & 63, gm2 = (g + 62) & 63;
    int gp1 = (g + 1) & 63,  gp2 = (g + 2) & 63;
    w[0]  = __shfl(a6, gm2); w[1]  = __shfl(a7, gm2);
    w[2]  = __shfl(a0, gm1); w[3]  = __shfl(a1, gm1);
    w[4]  = __shfl(a2, gm1); w[5]  = __shfl(a3, gm1);
    w[6]  = __shfl(a4, gm1); w[7]  = __shfl(a5, gm1);
    w[8]  = __shfl(a6, gm1); w[9]  = __shfl(a7, gm1);
    w[10] = a0; w[11] = a1; w[12] = a2; w[13] = a3;
    w[14] = a4; w[15] = a5; w[16] = a6; w[17] = a7;
    w[18] = __shfl(a0, gp1); w[19] = __shfl(a1, gp1);
    w[20] = __shfl(a2, gp1); w[21] = __shfl(a3, gp1);
    w[22] = __shfl(a4, gp1); w[23] = __shfl(a5, gp1);
    w[24] = __shfl(a6, gp1); w[25] = __shfl(a7, gp1);
    w[26] = __shfl(a0, gp2); w[27] = __shfl(a1, gp2);
}

__global__ __launch_bounds__(256, 2) void corr_kernel(
    const float* __restrict__ fr, const float* __restrict__ tpl,
    float* __restrict__ cc)
{
    int gid  = blockIdx.x;         // 448 blocks: b*14 + ug*2 + half
    int b    = gid / 14;
    int r    = gid % 14;
    int ug   = r >> 1;             // 0..6
    int half = r & 1;
    int u0   = ug * 3;

    const int g  = threadIdx.x & 63;
    const int wv = threadIdx.x >> 6;
    const int x0 = g * 8;
    const int ystart = half * 256 + wv * 64;

    const float* img = fr + (size_t)b * NPIX;

    float acc[3][NS];
#pragma unroll
    for (int s = 0; s < 3; ++s)
#pragma unroll
        for (int v = 0; v < NS; ++v) acc[s][v] = 0.f;

    float w0[28], w1[28], w2[28];
    // preload: row ystart-2 -> w1, ystart-1 -> w2
    load_wbuf(w1, tpl, (ystart - 2 - u0 + 10) & 511, g);
    load_wbuf(w2, tpl, (ystart - 1 - u0 + 10) & 511, g);

    auto row_step = [&](int y, float (&Wn)[28], float (&Wp1)[28], float (&Wp2)[28]) {
        load_wbuf(Wn, tpl, (y - u0 + 10) & 511, g);
        const float* ip = img + (size_t)y * WW + x0;
        float4 i0 = *(const float4*)ip;
        float4 i1 = *(const float4*)(ip + 4);
        float im[8] = { i0.x, i0.y, i0.z, i0.w, i1.x, i1.y, i1.z, i1.w };
#pragma unroll
        for (int v = 0; v < NS; ++v) {
            float s0 = acc[0][v], s1 = acc[1][v], s2 = acc[2][v];
#pragma unroll
            for (int p = 0; p < 8; ++p) {
                s0 += im[p] * Wn [p + 20 - v];   // template x = x0+p+10-v
                s1 += im[p] * Wp1[p + 20 - v];
                s2 += im[p] * Wp2[p + 20 - v];
            }
            acc[0][v] = s0; acc[1][v] = s1; acc[2][v] = s2;
        }
    };

    for (int i = 0; i < 21; ++i) {
        int y = ystart + 3 * i;
        row_step(y,     w0, w2, w1);
        row_step(y + 1, w1, w0, w2);
        row_step(y + 2, w2, w1, w0);
    }
    row_step(ystart + 63, w0, w2, w1);

    // reduce each of the 63 accumulators across the wave, lane0 atomics out
#pragma unroll
    for (int s = 0; s < 3; ++s)
#pragma unroll
        for (int v = 0; v < NS; ++v) {
            float t = acc[s][v];
#pragma unroll
            for (int off = 32; off; off >>= 1) t += __shfl_xor(t, off);
            if (g == 0)
                atomicAdd(&cc[((size_t)b * NS + (u0 + s)) * NS + v], t);
        }
}

// ---------------- Kernel S: argmax + log-parabola subpixel ------------------
__global__ __launch_bounds__(64) void argmax_kernel(
    const float* __restrict__ cc, const float* __restrict__ denom,
    const double* __restrict__ sum1, float* __restrict__ shifts)
{
    int b = blockIdx.x;
    const float* C = cc    + (size_t)b * NS * NS;
    const float* D = denom + (size_t)b * NS * NS;
    float corr = (float)(sum1[b] * sum1[32] * (1.0 / (double)NPIX));
    int l = threadIdx.x;
    float best = -1e30f; int bidx = NS * NS;
    for (int i = l; i < NS * NS; i += 64) {
        float v = fabsf(C[i] - corr) / D[i];
        if (v != v) v = 0.f;               // NaN -> 0 (matches reference)
        if (v > best) { best = v; bidx = i; }
    }
    for (int off = 32; off; off >>= 1) {
        float ov = __shfl_down(best, off);
        int   oi = __shfl_down(bidx, off);
        if (ov > best || (ov == best && oi < bidx)) { best = ov; bidx = oi; }
    }
    if (l == 0) {
        int shx = bidx / NS, shy = bidx % NS;
        auto nccAt = [&](int i, int j) -> float {
            i = (i < 0) ? i + NS : i; i = (i > NS - 1) ? NS - 1 : i;  // jnp wrap-then-clamp
            j = (j < 0) ? j + NS : j; j = (j > NS - 1) ? NS - 1 : j;
            float v = fabsf(C[i * NS + j] - corr) / D[i * NS + j];
            if (v != v) v = 0.f;
            return v;
        };
        float lc  = logf(nccAt(shx, shy));
        float lxm = logf(nccAt(shx - 1, shy));
        float lxp = logf(nccAt(shx + 1, shy));
        float lym = logf(nccAt(shx, shy - 1));
        float lyp = logf(nccAt(shx, shy + 1));
        float shxn = -(float)(shx - 10) - (lxm - lxp) / (2.f * lxm - 4.f * lc + 2.f * lxp);
        float shyn = -(float)(shy - 10) - (lym - lyp) / (2.f * lym - 4.f * lc + 2.f * lyp);
        shifts[b]      = shxn;   // dy
        shifts[32 + b] = shyn;   // dx
    }
}

// ---------------- Kernel B: bilinear warp + transposed write ----------------
__device__ __forceinline__ float samp(const float* __restrict__ img, int y, int x) {
    bool valid = (y >= 0) & (y < HH) & (x >= 0) & (x < WW);
    int yc = min(max(y, 0), HH - 1), xc = min(max(x, 0), WW - 1);
    float v = img[(size_t)yc * WW + xc];
    return valid ? v : 0.f;
}

__global__ __launch_bounds__(256) void warp_kernel(
    const float* __restrict__ fr, const float* __restrict__ shifts,
    float* __restrict__ out)
{
    int b  = blockIdx.z;
    int h0 = blockIdx.y * 32;
    int w0 = blockIdx.x * 32;
    float dy = shifts[b], dx = shifts[32 + b];
    const float* img = fr + (size_t)b * NPIX;
    __shared__ float tile[32][33];
    int tx = threadIdx.x & 31;
    int tz = threadIdx.x >> 5;
#pragma unroll
    for (int s = 0; s < 4; ++s) {
        int h = h0 + tz + 8 * s;
        int w = w0 + tx;
        float yq = (float)h - dy;
        float xq = (float)w - dx;
        float y0f = floorf(yq), x0f = floorf(xq);
        float wy = yq - y0f, wx = xq - x0f;
        int y0 = (int)y0f, x0 = (int)x0f;
        float v00 = samp(img, y0,     x0);
        float v01 = samp(img, y0,     x0 + 1);
        float v10 = samp(img, y0 + 1, x0);
        float v11 = samp(img, y0 + 1, x0 + 1);
        float val = v00 * (1.f - wy) * (1.f - wx) + v01 * (1.f - wy) * wx
                  + v10 * wy * (1.f - wx)         + v11 * wy * wx;
        tile[tz + 8 * s][tx] = val;
    }
    __syncthreads();
#pragma unroll
    for (int s = 0; s < 4; ++s) {
        int hh = tx;
        int ww = tz + 8 * s;
        out[(size_t)b * NPIX + (size_t)(w0 + ww) * HH + (h0 + hh)] = tile[hh][ww];
    }
}

// ---------------- launch ----------------------------------------------------
extern "C" void kernel_launch(void* const* d_in, const int* in_sizes, int n_in,
                              void* d_out, int out_size, void* d_ws, size_t ws_size,
                              hipStream_t stream) {
    const float* fr  = (const float*)d_in[0];   // (1,32,512,512,1) flat
    const float* tpl = (const float*)d_in[1];   // (512,512)
    float* out = (float*)d_out;
    char* ws = (char*)d_ws;

    // ws layout (total ~2.9 MB)
    double* sum1   = (double*)(ws + 0);          // 33 doubles
    double* sum2   = (double*)(ws + 512);        // 33 doubles
    float*  cc     = (float*) (ws + 4096);       // 32*441 floats (zeroed)
    float*  shifts = (float*) (ws + 61440);      // 64 floats
    float*  denom  = (float*) (ws + 65536);      // 32*441 floats
    float*  cs1    = (float*) (ws + 131072);     // 32*21*512 floats
    float*  cs2    = (float*) (ws + 1507328);    // 32*21*512 floats

    hipMemsetAsync(ws, 0, 61440, stream);        // zero sums + cc

    colsum_kernel<<<264, 64, 0, stream>>>(fr, tpl, cs1, cs2, sum1, sum2);
    denom_kernel <<<(NB * NS * NS + 3) / 4, 256, 0, stream>>>(cs1, cs2, sum1, sum2, denom);
    corr_kernel  <<<448, 256, 0, stream>>>(fr, tpl, cc);
    argmax_kernel<<<32, 64, 0, stream>>>(cc, denom, sum1, shifts);
    warp_kernel  <<<dim3(16, 16, 32), 256, 0, stream>>>(fr, shifts, out);
}

// Round 5
// 263.523 us; speedup vs baseline: 1.9348x; 1.0630x over previous
//
#include <hip/hip_runtime.h>
#include <math.h>

#define HH 512
#define WW 512
#define NPIX (HH*WW)
#define NB 32
#define NS 21           // 2*MS+1 shifts per axis
#define KWIN 492        // window size (H - 2*10)

// ---------------- Kernel W1a: interior column sums (rows 20..491) -----------
// blocks 0..255: (b, ygroup of 59 rows) -> fp32 atomicAdd into I1/I2[b][x]
// blocks 256..263: template 64-row group -> atomicAdd sum1[32], sum2[32]
__global__ __launch_bounds__(256) void colsum_phase1(
    const float* __restrict__ fr, const float* __restrict__ tpl,
    float* __restrict__ I1, float* __restrict__ I2,
    double* __restrict__ sum1, double* __restrict__ sum2)
{
    int blk = blockIdx.x;
    int t   = threadIdx.x;
    if (blk < 256) {
        int b  = blk >> 3;
        int yg = blk & 7;
        int y0 = 20 + 59 * yg;
        const float* img = fr + (size_t)b * NPIX;
        int xa = t, xb = t + 256;
        float s1a = 0.f, s2a = 0.f, s1b = 0.f, s2b = 0.f;
        for (int y = y0; y < y0 + 59; ++y) {
            float va = img[(size_t)y * WW + xa];
            float vb = img[(size_t)y * WW + xb];
            s1a += va; s2a += va * va;
            s1b += vb; s2b += vb * vb;
        }
        atomicAdd(&I1[b * WW + xa], s1a); atomicAdd(&I2[b * WW + xa], s2a);
        atomicAdd(&I1[b * WW + xb], s1b); atomicAdd(&I2[b * WW + xb], s2b);
    } else {
        int gq = blk - 256;            // 0..7 -> rows [64gq, 64gq+64)
        int y0 = 64 * gq;
        int xa = t, xb = t + 256;
        float s1a = 0.f, s2a = 0.f, s1b = 0.f, s2b = 0.f;
        for (int y = y0; y < y0 + 64; ++y) {
            float va = tpl[(size_t)y * WW + xa];
            float vb = tpl[(size_t)y * WW + xb];
            s1a += va; s2a += va * va;
            s1b += vb; s2b += vb * vb;
        }
        double d1 = (double)s1a + (double)s1b;
        double d2 = (double)s2a + (double)s2b;
        for (int off = 32; off; off >>= 1) {
            d1 += __shfl_down(d1, off);
            d2 += __shfl_down(d2, off);
        }
        __shared__ double r1[4], r2[4];
        int lane = t & 63, wv = t >> 6;
        if (lane == 0) { r1[wv] = d1; r2[wv] = d2; }
        __syncthreads();
        if (t == 0) {
            atomicAdd(&sum1[32], r1[0] + r1[1] + r1[2] + r1[3]);
            atomicAdd(&sum2[32], r2[0] + r2[1] + r2[2] + r2[3]);
        }
    }
}

// ---------------- Kernel W1b: edges + sliding windows + frame totals --------
__global__ __launch_bounds__(512) void colsum_combine(
    const float* __restrict__ fr, const float* __restrict__ I1,
    const float* __restrict__ I2, float* __restrict__ cs1,
    float* __restrict__ cs2, double* __restrict__ sum1)
{
    int b = blockIdx.x;
    int x = threadIdx.x;
    const float* img = fr + (size_t)b * NPIX;
    float top[20], bot[20];
#pragma unroll
    for (int y = 0; y < 20; ++y) top[y] = img[(size_t)y * WW + x];
#pragma unroll
    for (int y = 0; y < 20; ++y) bot[y] = img[(size_t)(492 + y) * WW + x];

    float t1 = 0.f, t2 = 0.f, b1 = 0.f, b2 = 0.f;
#pragma unroll
    for (int y = 0; y < 20; ++y) {
        t1 += top[y]; t2 += top[y] * top[y];
        b1 += bot[y]; b2 += bot[y] * bot[y];
    }
    float i1 = I1[b * WW + x], i2 = I2[b * WW + x];

    // frame total -> sum1[b]
    double tot = (double)i1 + (double)t1 + (double)b1;
    for (int off = 32; off; off >>= 1) tot += __shfl_down(tot, off);
    __shared__ double red[8];
    int lane = x & 63, wv = x >> 6;
    if (lane == 0) red[wv] = tot;
    __syncthreads();
    if (x == 0) {
        double s = 0.0;
        for (int i = 0; i < 8; ++i) s += red[i];
        sum1[b] = s;
    }

    // sliding windows: cs(u) = I + sum(top[u..19]) + sum(bot[0..u-1])
    float s1 = i1 + t1, s2 = i2 + t2;
    size_t base = (size_t)b * NS * WW + x;
    cs1[base] = s1; cs2[base] = s2;
#pragma unroll
    for (int u = 1; u < NS; ++u) {
        float a = top[u-1], c = bot[u-1];
        s1 += c - a;
        s2 += c * c - a * a;
        cs1[base + (size_t)u * WW] = s1;
        cs2[base + (size_t)u * WW] = s2;
    }
}

// ---------------- Kernel W2: window sums -> denominator (wave per triple) ---
__global__ __launch_bounds__(256) void denom_kernel(
    const float* __restrict__ cs1, const float* __restrict__ cs2,
    const double* __restrict__ sum1, const double* __restrict__ sum2,
    float* __restrict__ denom)
{
    int wid  = blockIdx.x * 4 + (threadIdx.x >> 6);   // one wave per (b,u,v)
    int lane = threadIdx.x & 63;
    if (wid >= NB * NS * NS) return;
    int v  = wid % NS;
    int bu = wid / NS;
    const float* r1 = cs1 + (size_t)bu * WW + v;
    const float* r2 = cs2 + (size_t)bu * WW + v;
    double s1 = 0.0, s2 = 0.0;
    for (int x = lane; x < KWIN; x += 64) { s1 += (double)r1[x]; s2 += (double)r2[x]; }
    for (int off = 32; off; off >>= 1) {
        s1 += __shfl_down(s1, off);
        s2 += __shfl_down(s2, off);
    }
    if (lane == 0) {
        const double inv = 1.0 / ((double)KWIN * (double)KWIN);
        double m1 = s1 * inv, m2 = s2 * inv;
        double var = m2 - (m1 * m1) * inv + 1e-8;   // reference's formula
        if (var < 0.0) var = 0.0;
        double tv = sum2[32] - sum1[32] * sum1[32] * (1.0 / (double)NPIX) + 1e-8;
        denom[wid] = (float)sqrt(tv * var);
    }
}

// ---------------- Kernel C: raw circular cross-correlation, LDS-free --------
// rawcc[b][u][v] = sum_{y,x} img[y,x] * tpl[(y-u+10)&511, (x-v+10)&511]
// u-PAIRS per block (2-buffer register ring, spill-free ~120 VGPR), plus a
// single-u instantiation for u=20. No LDS staging, halos via __shfl.
__device__ __forceinline__ void load_wbuf(float (&w)[28], const float* __restrict__ tpl,
                                          int ty, int g)
{
    const float* trow = tpl + (size_t)ty * WW;
    float4 t0 = *(const float4*)(trow + 8 * g);
    float4 t1 = *(const float4*)(trow + 8 * g + 4);
    float a0 = t0.x, a1 = t0.y, a2 = t0.z, a3 = t0.w;
    float a4 = t1.x, a5 = t1.y, a6 = t1.z, a7 = t1.w;
    int gm1 = (g + 63) & 63, gm2 = (g + 62) & 63;
    int gp1 = (g + 1) & 63,  gp2 = (g + 2) & 63;
    w[0]  = __shfl(a6, gm2); w[1]  = __shfl(a7, gm2);
    w[2]  = __shfl(a0, gm1); w[3]  = __shfl(a1, gm1);
    w[4]  = __shfl(a2, gm1); w[5]  = __shfl(a3, gm1);
    w[6]  = __shfl(a4, gm1); w[7]  = __shfl(a5, gm1);
    w[8]  = __shfl(a6, gm1); w[9]  = __shfl(a7, gm1);
    w[10] = a0; w[11] = a1; w[12] = a2; w[13] = a3;
    w[14] = a4; w[15] = a5; w[16] = a6; w[17] = a7;
    w[18] = __shfl(a0, gp1); w[19] = __shfl(a1, gp1);
    w[20] = __shfl(a2, gp1); w[21] = __shfl(a3, gp1);
    w[22] = __shfl(a4, gp1); w[23] = __shfl(a5, gp1);
    w[24] = __shfl(a6, gp1); w[25] = __shfl(a7, gp1);
    w[26] = __shfl(a0, gp2); w[27] = __shfl(a1, gp2);
}

__global__ __launch_bounds__(256, 3) void corr_pair_kernel(
    const float* __restrict__ fr, const float* __restrict__ tpl,
    float* __restrict__ cc)
{
    int gid = blockIdx.x;          // 1280 blocks: b*40 + ug*4 + q
    int b   = gid / 40;
    int rem = gid % 40;
    int ug  = rem >> 2;            // 0..9
    int q   = rem & 3;
    int u0  = ug * 2;

    const int g  = threadIdx.x & 63;
    const int wv = threadIdx.x >> 6;
    const int x0 = g * 8;
    const int ystart = q * 128 + wv * 32;

    const float* img = fr + (size_t)b * NPIX;

    float acc0[NS], acc1[NS];
#pragma unroll
    for (int v = 0; v < NS; ++v) { acc0[v] = 0.f; acc1[v] = 0.f; }

    float w0[28], w1[28];
    load_wbuf(w1, tpl, (ystart - 1 - u0 + 10) & 511, g);

    auto row_step = [&](int y, float (&Wn)[28], float (&Wp)[28]) {
        load_wbuf(Wn, tpl, (y - u0 + 10) & 511, g);
        const float* ip = img + (size_t)y * WW + x0;
        float4 i0 = *(const float4*)ip;
        float4 i1 = *(const float4*)(ip + 4);
        float im[8] = { i0.x, i0.y, i0.z, i0.w, i1.x, i1.y, i1.z, i1.w };
#pragma unroll
        for (int v = 0; v < NS; ++v) {
            float s0 = acc0[v], s1 = acc1[v];
#pragma unroll
            for (int p = 0; p < 8; ++p) {
                s0 += im[p] * Wn[p + 20 - v];   // shift u0   at row y
                s1 += im[p] * Wp[p + 20 - v];   // shift u0+1 at row y
            }
            acc0[v] = s0; acc1[v] = s1;
        }
    };

    for (int i = 0; i < 16; ++i) {
        int y = ystart + 2 * i;
        row_step(y,     w0, w1);
        row_step(y + 1, w1, w0);
    }

#pragma unroll
    for (int v = 0; v < NS; ++v) {
        float t0 = acc0[v], t1 = acc1[v];
#pragma unroll
        for (int off = 32; off; off >>= 1) {
            t0 += __shfl_xor(t0, off);
            t1 += __shfl_xor(t1, off);
        }
        if (g == 0) {
            atomicAdd(&cc[((size_t)b * NS + u0)     * NS + v], t0);
            atomicAdd(&cc[((size_t)b * NS + u0 + 1) * NS + v], t1);
        }
    }
}

__global__ __launch_bounds__(256, 4) void corr_single_kernel(
    const float* __restrict__ fr, const float* __restrict__ tpl,
    float* __restrict__ cc)
{
    int gid = blockIdx.x;          // 128 blocks: b*4 + q
    int b   = gid >> 2;
    int q   = gid & 3;
    const int u0 = 20;

    const int g  = threadIdx.x & 63;
    const int wv = threadIdx.x >> 6;
    const int x0 = g * 8;
    const int ystart = q * 128 + wv * 32;

    const float* img = fr + (size_t)b * NPIX;

    float acc[NS];
#pragma unroll
    for (int v = 0; v < NS; ++v) acc[v] = 0.f;

    float w0[28];
    for (int y = ystart; y < ystart + 32; ++y) {
        load_wbuf(w0, tpl, (y - u0 + 10) & 511, g);
        const float* ip = img + (size_t)y * WW + x0;
        float4 i0 = *(const float4*)ip;
        float4 i1 = *(const float4*)(ip + 4);
        float im[8] = { i0.x, i0.y, i0.z, i0.w, i1.x, i1.y, i1.z, i1.w };
#pragma unroll
        for (int v = 0; v < NS; ++v) {
            float s = acc[v];
#pragma unroll
            for (int p = 0; p < 8; ++p)
                s += im[p] * w0[p + 20 - v];
            acc[v] = s;
        }
    }

#pragma unroll
    for (int v = 0; v < NS; ++v) {
        float t = acc[v];
#pragma unroll
        for (int off = 32; off; off >>= 1) t += __shfl_xor(t, off);
        if (g == 0)
            atomicAdd(&cc[((size_t)b * NS + u0) * NS + v], t);
    }
}

// ---------------- Kernel S: argmax + log-parabola subpixel ------------------
__global__ __launch_bounds__(64) void argmax_kernel(
    const float* __restrict__ cc, const float* __restrict__ denom,
    const double* __restrict__ sum1, float* __restrict__ shifts)
{
    int b = blockIdx.x;
    const float* C = cc    + (size_t)b * NS * NS;
    const float* D = denom + (size_t)b * NS * NS;
    float corr = (float)(sum1[b] * sum1[32] * (1.0 / (double)NPIX));
    int l = threadIdx.x;
    float best = -1e30f; int bidx = NS * NS;
    for (int i = l; i < NS * NS; i += 64) {
        float v = fabsf(C[i] - corr) / D[i];
        if (v != v) v = 0.f;               // NaN -> 0 (matches reference)
        if (v > best) { best = v; bidx = i; }
    }
    for (int off = 32; off; off >>= 1) {
        float ov = __shfl_down(best, off);
        int   oi = __shfl_down(bidx, off);
        if (ov > best || (ov == best && oi < bidx)) { best = ov; bidx = oi; }
    }
    if (l == 0) {
        int shx = bidx / NS, shy = bidx % NS;
        auto nccAt = [&](int i, int j) -> float {
            i = (i < 0) ? i + NS : i; i = (i > NS - 1) ? NS - 1 : i;  // jnp wrap-then-clamp
            j = (j < 0) ? j + NS : j; j = (j > NS - 1) ? NS - 1 : j;
            float v = fabsf(C[i * NS + j] - corr) / D[i * NS + j];
            if (v != v) v = 0.f;
            return v;
        };
        float lc  = logf(nccAt(shx, shy));
        float lxm = logf(nccAt(shx - 1, shy));
        float lxp = logf(nccAt(shx + 1, shy));
        float lym = logf(nccAt(shx, shy - 1));
        float lyp = logf(nccAt(shx, shy + 1));
        float shxn = -(float)(shx - 10) - (lxm - lxp) / (2.f * lxm - 4.f * lc + 2.f * lxp);
        float shyn = -(float)(shy - 10) - (lym - lyp) / (2.f * lym - 4.f * lc + 2.f * lyp);
        shifts[b]      = shxn;   // dy
        shifts[32 + b] = shyn;   // dx
    }
}

// ---------------- Kernel B: bilinear warp + transposed write ----------------
__device__ __forceinline__ float samp(const float* __restrict__ img, int y, int x) {
    bool valid = (y >= 0) & (y < HH) & (x >= 0) & (x < WW);
    int yc = min(max(y, 0), HH - 1), xc = min(max(x, 0), WW - 1);
    float v = img[(size_t)yc * WW + xc];
    return valid ? v : 0.f;
}

__global__ __launch_bounds__(256) void warp_kernel(
    const float* __restrict__ fr, const float* __restrict__ shifts,
    float* __restrict__ out)
{
    int b  = blockIdx.z;
    int h0 = blockIdx.y * 32;
    int w0 = blockIdx.x * 32;
    float dy = shifts[b], dx = shifts[32 + b];
    const float* img = fr + (size_t)b * NPIX;
    __shared__ float tile[32][33];
    int tx = threadIdx.x & 31;
    int tz = threadIdx.x >> 5;
#pragma unroll
    for (int s = 0; s < 4; ++s) {
        int h = h0 + tz + 8 * s;
        int w = w0 + tx;
        float yq = (float)h - dy;
        float xq = (float)w - dx;
        float y0f = floorf(yq), x0f = floorf(xq);
        float wy = yq - y0f, wx = xq - x0f;
        int y0 = (int)y0f, x0 = (int)x0f;
        float v00 = samp(img, y0,     x0);
        float v01 = samp(img, y0,     x0 + 1);
        float v10 = samp(img, y0 + 1, x0);
        float v11 = samp(img, y0 + 1, x0 + 1);
        float val = v00 * (1.f - wy) * (1.f - wx) + v01 * (1.f - wy) * wx
                  + v10 * wy * (1.f - wx)         + v11 * wy * wx;
        tile[tz + 8 * s][tx] = val;
    }
    __syncthreads();
#pragma unroll
    for (int s = 0; s < 4; ++s) {
        int hh = tx;
        int ww = tz + 8 * s;
        out[(size_t)b * NPIX + (size_t)(w0 + ww) * HH + (h0 + hh)] = tile[hh][ww];
    }
}

// ---------------- launch ----------------------------------------------------
extern "C" void kernel_launch(void* const* d_in, const int* in_sizes, int n_in,
                              void* d_out, int out_size, void* d_ws, size_t ws_size,
                              hipStream_t stream) {
    const float* fr  = (const float*)d_in[0];   // (1,32,512,512,1) flat
    const float* tpl = (const float*)d_in[1];   // (512,512)
    float* out = (float*)d_out;
    char* ws = (char*)d_ws;

    // ws layout (~3.0 MB)
    double* sum1   = (double*)(ws + 0);          // 33 doubles
    double* sum2   = (double*)(ws + 512);        // 33 doubles
    float*  cc     = (float*) (ws + 4096);       // 32*441 floats
    float*  I1     = (float*) (ws + 61440);      // 32*512 floats
    float*  I2     = (float*) (ws + 126976);     // 32*512 floats
    float*  shifts = (float*) (ws + 196608);     // 64 floats
    float*  denom  = (float*) (ws + 200704);     // 32*441 floats
    float*  cs1    = (float*) (ws + 262144);     // 32*21*512 floats
    float*  cs2    = (float*) (ws + 1638400);    // 32*21*512 floats

    hipMemsetAsync(ws, 0, 192512, stream);       // zero sums + cc + I1/I2

    colsum_phase1 <<<264, 256, 0, stream>>>(fr, tpl, I1, I2, sum1, sum2);
    colsum_combine<<<32, 512, 0, stream>>>(fr, I1, I2, cs1, cs2, sum1);
    denom_kernel  <<<(NB * NS * NS + 3) / 4, 256, 0, stream>>>(cs1, cs2, sum1, sum2, denom);
    corr_pair_kernel  <<<1280, 256, 0, stream>>>(fr, tpl, cc);
    corr_single_kernel<<<128, 256, 0, stream>>>(fr, tpl, cc);
    argmax_kernel <<<32, 64, 0, stream>>>(cc, denom, sum1, shifts);
    warp_kernel   <<<dim3(16, 16, 32), 256, 0, stream>>>(fr, shifts, out);
}